// Round 2
// baseline (807.171 us; speedup 1.0000x reference)
//
#include <hip/hip_runtime.h>

typedef unsigned short u16t;
typedef __attribute__((ext_vector_type(8))) short bf8;
typedef __attribute__((ext_vector_type(4))) float f4;
typedef __attribute__((ext_vector_type(4))) unsigned int u4;

#define DEV __device__ __forceinline__

DEV u16t f2b(float f){
  unsigned u = __float_as_uint(f);
  u = (u + 0x7fffu + ((u >> 16) & 1u)) >> 16;
  return (u16t)u;
}
DEV float b2f(u16t u){ return __uint_as_float(((unsigned)u) << 16); }
DEV float sigm(float x){ return 1.f / (1.f + __expf(-x)); }

// B=2, SEQ=4096, D_MODEL=2048, D_INNER=2048, D_STATE=128, D_XB=512, D_CONV=4
// NHEADS=16, HEADDIM=128, NKV=4, N_REP=4, CHUNK=256, CONV_DIM=3072, D_IN_PROJ=5136
constexpr int KDIM   = 2048;
constexpr int DPROJ  = 5136;
constexpr int BLROWS = 8192;

#define MFMA16(a,b,c) __builtin_amdgcn_mfma_f32_16x16x32_bf16((a),(b),(c),0,0,0)

// ---------------------------------------------------------------- K0: f32->bf16
__global__ __launch_bounds__(256) void k_cvt(const float* __restrict__ src,
                                             u16t* __restrict__ dst, int n4){
  int i = blockIdx.x * 256 + threadIdx.x;
  if (i < n4){
    float4 v = ((const float4*)src)[i];
    ushort4 o;
    o.x = f2b(v.x); o.y = f2b(v.y); o.z = f2b(v.z); o.w = f2b(v.w);
    ((ushort4*)dst)[i] = o;
  }
}

// ---------------------------------------------------------------- K1: in_proj GEMM
// A[8192][2048] bf16, B[5136][2048] bf16 -> z16 / xbc16 / dtraw split outputs.
__global__ __launch_bounds__(256) void k_gemm_in(const u16t* __restrict__ A,
                                                 const u16t* __restrict__ B,
                                                 u16t* __restrict__ z16,
                                                 u16t* __restrict__ xbc16,
                                                 float* __restrict__ dtraw){
  __shared__ __align__(16) char As[16384];
  __shared__ __align__(16) char Bs[16384];
  const int tid = threadIdx.x;
  const int lane = tid & 63, w = tid >> 6;
  const int lo = lane & 15, hi = lane >> 4;
  const int m0 = blockIdx.y << 7, n0 = blockIdx.x << 7;
  const int wr = (w >> 1) << 6, wc = (w & 1) << 6;
  f4 zero = {0.f, 0.f, 0.f, 0.f};
  f4 acc[4][4];
#pragma unroll
  for (int i = 0; i < 4; ++i)
#pragma unroll
    for (int j = 0; j < 4; ++j) acc[i][j] = zero;
  for (int kt = 0; kt < 32; ++kt){
    u4 av[4], bv[4];
#pragma unroll
    for (int q = 0; q < 4; ++q){
      int idx = q * 256 + tid;
      int row = idx >> 3, kc = idx & 7;
      av[q] = *(const u4*)(A + (size_t)(m0 + row) * KDIM + (kt << 6) + (kc << 3));
      int rb = n0 + row;
      u4 t = {0u, 0u, 0u, 0u};
      if (rb < DPROJ) t = *(const u4*)(B + (size_t)rb * KDIM + (kt << 6) + (kc << 3));
      bv[q] = t;
    }
    __syncthreads();
#pragma unroll
    for (int q = 0; q < 4; ++q){
      int idx = q * 256 + tid;
      int row = idx >> 3, kc = idx & 7;
      int off = ((row << 7) + (kc << 4)) ^ ((row & 7) << 4);
      *(u4*)(As + off) = av[q];
      *(u4*)(Bs + off) = bv[q];
    }
    __syncthreads();
#pragma unroll
    for (int kk = 0; kk < 2; ++kk){
      bf8 af[4], bb[4];
#pragma unroll
      for (int mb = 0; mb < 4; ++mb){
        int row = wr + mb * 16 + lo;
        int off = ((row << 7) + (kk << 6) + (hi << 4)) ^ ((row & 7) << 4);
        af[mb] = *(const bf8*)(As + off);
      }
#pragma unroll
      for (int nb = 0; nb < 4; ++nb){
        int row = wc + nb * 16 + lo;
        int off = ((row << 7) + (kk << 6) + (hi << 4)) ^ ((row & 7) << 4);
        bb[nb] = *(const bf8*)(Bs + off);
      }
#pragma unroll
      for (int mb = 0; mb < 4; ++mb)
#pragma unroll
        for (int nb = 0; nb < 4; ++nb)
          acc[mb][nb] = MFMA16(af[mb], bb[nb], acc[mb][nb]);
    }
  }
#pragma unroll
  for (int mb = 0; mb < 4; ++mb)
#pragma unroll
    for (int nb = 0; nb < 4; ++nb)
#pragma unroll
      for (int i = 0; i < 4; ++i){
        int r = m0 + wr + mb * 16 + hi * 4 + i;
        int col = n0 + wc + nb * 16 + lo;
        float v = acc[mb][nb][i];
        if (col < 2048)       z16[(size_t)r * 2048 + col] = f2b(v);
        else if (col < 5120)  xbc16[(size_t)r * 3072 + (col - 2048)] = f2b(v);
        else if (col < 5136)  dtraw[(size_t)r * 16 + (col - 5120)] = v;
      }
}

// ---------------------------------------------------------------- K9: out_proj GEMM
__global__ __launch_bounds__(256) void k_gemm_out(const u16t* __restrict__ A,
                                                  const u16t* __restrict__ B,
                                                  float* __restrict__ C){
  __shared__ __align__(16) char As[16384];
  __shared__ __align__(16) char Bs[16384];
  const int tid = threadIdx.x;
  const int lane = tid & 63, w = tid >> 6;
  const int lo = lane & 15, hi = lane >> 4;
  const int m0 = blockIdx.y << 7, n0 = blockIdx.x << 7;
  const int wr = (w >> 1) << 6, wc = (w & 1) << 6;
  f4 zero = {0.f, 0.f, 0.f, 0.f};
  f4 acc[4][4];
#pragma unroll
  for (int i = 0; i < 4; ++i)
#pragma unroll
    for (int j = 0; j < 4; ++j) acc[i][j] = zero;
  for (int kt = 0; kt < 32; ++kt){
    u4 av[4], bv[4];
#pragma unroll
    for (int q = 0; q < 4; ++q){
      int idx = q * 256 + tid;
      int row = idx >> 3, kc = idx & 7;
      av[q] = *(const u4*)(A + (size_t)(m0 + row) * KDIM + (kt << 6) + (kc << 3));
      bv[q] = *(const u4*)(B + (size_t)(n0 + row) * KDIM + (kt << 6) + (kc << 3));
    }
    __syncthreads();
#pragma unroll
    for (int q = 0; q < 4; ++q){
      int idx = q * 256 + tid;
      int row = idx >> 3, kc = idx & 7;
      int off = ((row << 7) + (kc << 4)) ^ ((row & 7) << 4);
      *(u4*)(As + off) = av[q];
      *(u4*)(Bs + off) = bv[q];
    }
    __syncthreads();
#pragma unroll
    for (int kk = 0; kk < 2; ++kk){
      bf8 af[4], bb[4];
#pragma unroll
      for (int mb = 0; mb < 4; ++mb){
        int row = wr + mb * 16 + lo;
        int off = ((row << 7) + (kk << 6) + (hi << 4)) ^ ((row & 7) << 4);
        af[mb] = *(const bf8*)(As + off);
      }
#pragma unroll
      for (int nb = 0; nb < 4; ++nb){
        int row = wc + nb * 16 + lo;
        int off = ((row << 7) + (kk << 6) + (hi << 4)) ^ ((row & 7) << 4);
        bb[nb] = *(const bf8*)(Bs + off);
      }
#pragma unroll
      for (int mb = 0; mb < 4; ++mb)
#pragma unroll
        for (int nb = 0; nb < 4; ++nb)
          acc[mb][nb] = MFMA16(af[mb], bb[nb], acc[mb][nb]);
    }
  }
#pragma unroll
  for (int mb = 0; mb < 4; ++mb)
#pragma unroll
    for (int nb = 0; nb < 4; ++nb)
#pragma unroll
      for (int i = 0; i < 4; ++i){
        int r = m0 + wr + mb * 16 + hi * 4 + i;
        int col = n0 + wc + nb * 16 + lo;
        C[(size_t)r * 2048 + col] = acc[mb][nb][i];
      }
}

// ---------------------------------------------------------------- K2: conv + silu
__global__ __launch_bounds__(256) void k_conv(const u16t* __restrict__ xbc,
                                              const float* __restrict__ cw,
                                              const float* __restrict__ cb,
                                              u16t* __restrict__ xf16,
                                              u16t* __restrict__ Bg,
                                              u16t* __restrict__ Cgb){
  int ch = blockIdx.x * 256 + threadIdx.x;
  int bl = blockIdx.y;
  int l = bl & 4095;
  const u16t* zc = xbc + (size_t)bl * 3072 + ch;
  float a = cb[ch];
  if (l >= 3) a += b2f(zc[-3 * 3072]) * cw[ch * 4 + 0];
  if (l >= 2) a += b2f(zc[-2 * 3072]) * cw[ch * 4 + 1];
  if (l >= 1) a += b2f(zc[-1 * 3072]) * cw[ch * 4 + 2];
  a += b2f(zc[0]) * cw[ch * 4 + 3];
  float s = a * sigm(a);
  if (ch < 512)       xf16[(size_t)bl * 512 + ch] = f2b(s);
  else if (ch < 1024) Bg[(size_t)bl * 512 + (ch - 512)] = f2b(s);
  else                Cgb[(size_t)bl * 2048 + (ch - 1024)] = f2b(s);
}

// ---------------------------------------------------------------- K3: dt softplus
__global__ __launch_bounds__(256) void k_dt(const float* __restrict__ dtraw,
                                            const float* __restrict__ dtb,
                                            float* __restrict__ dtv){
  int bl = blockIdx.x * 256 + threadIdx.x;
  int b = bl >> 12, l = bl & 4095;
#pragma unroll
  for (int h = 0; h < 16; ++h){
    float x = dtraw[(size_t)bl * 16 + h] + dtb[h];
    float sp = (x > 15.f) ? x : log1pf(__expf(x));
    dtv[((size_t)(b * 16 + h)) * 4096 + l] = sp;
  }
}

// ---------------------------------------------------------------- K4: chunk cumsum
__global__ __launch_bounds__(256) void k_prep(const float* __restrict__ dtv,
                                              const float* __restrict__ alog,
                                              float* __restrict__ Acs,
                                              float* __restrict__ dstv,
                                              float* __restrict__ cdec){
  int c = blockIdx.x, h = blockIdx.y, b = blockIdx.z;
  int tid = threadIdx.x;
  int bhc = (b * 16 + h) * 16 + c;
  __shared__ float sb_[2][256];
  float An = -__expf(alog[h]);
  float dA = dtv[((size_t)(b * 16 + h)) * 4096 + c * 256 + tid] * An;
  sb_[0][tid] = dA;
  __syncthreads();
  int src = 0;
  for (int off = 1; off < 256; off <<= 1){
    float v = sb_[src][tid];
    if (tid >= off) v += sb_[src][tid - off];
    sb_[src ^ 1][tid] = v;
    __syncthreads();
    src ^= 1;
  }
  float a = sb_[src][tid];
  float ae = sb_[src][255];
  Acs[(size_t)bhc * 256 + tid]  = a;
  dstv[(size_t)bhc * 256 + tid] = __expf(ae - a);
  if (tid == 0) cdec[bhc] = __expf(ae);
}

// ---------------------------------------------------------------- K5: repack transposes
__global__ __launch_bounds__(256) void k_repack(const u16t* __restrict__ xf16,
                                                const float* __restrict__ dtv,
                                                const u16t* __restrict__ Bg,
                                                u16t* __restrict__ xdtT,
                                                u16t* __restrict__ BgT){
  int c = blockIdx.x, h = blockIdx.y, b = blockIdx.z;
  int tid = threadIdx.x;
  int bhc = (b * 16 + h) * 16 + c;
  int kv = h >> 2;
  __shared__ float tile[128][65];
  for (int st = 0; st < 4; ++st){
#pragma unroll
    for (int i = 0; i < 32; ++i){
      int idx = i * 256 + tid;
      int sl = idx >> 7, p = idx & 127;
      int l = c * 256 + st * 64 + sl;
      size_t bl = (size_t)b * 4096 + l;
      tile[p][sl] = b2f(xf16[bl * 512 + kv * 128 + p]) * dtv[((size_t)(b * 16 + h)) * 4096 + l];
    }
    __syncthreads();
#pragma unroll
    for (int i = 0; i < 32; ++i){
      int idx = i * 256 + tid;
      int p = idx >> 6, sl = idx & 63;
      xdtT[(size_t)bhc * 32768 + p * 256 + st * 64 + sl] = f2b(tile[p][sl]);
    }
    __syncthreads();
  }
  if (h < 4){
    for (int st = 0; st < 4; ++st){
#pragma unroll
      for (int i = 0; i < 32; ++i){
        int idx = i * 256 + tid;
        int sl = idx >> 7, n = idx & 127;
        size_t bl = (size_t)b * 4096 + c * 256 + st * 64 + sl;
        tile[n][sl] = (float)Bg[bl * 512 + h * 128 + n];
      }
      __syncthreads();
#pragma unroll
      for (int i = 0; i < 32; ++i){
        int idx = i * 256 + tid;
        int n = idx >> 6, sl = idx & 63;
        BgT[((size_t)(b * 4 + h) * 128 + n) * 4096 + c * 256 + st * 64 + sl] = (u16t)tile[n][sl];
      }
      __syncthreads();
    }
  }
}

// ---------------------------------------------------------------- K6: chunk states
// states16[bhc][p][n] = sum_l xdt[p][l]*dstv[l]*B[l][n], decay applied in-register.
__global__ __launch_bounds__(256) void k_states(const u16t* __restrict__ xdtT,
                                                const float* __restrict__ dstv,
                                                const u16t* __restrict__ BgT,
                                                u16t* __restrict__ states16){
  int c = blockIdx.x, h = blockIdx.y, b = blockIdx.z;
  int tid = threadIdx.x, lane = tid & 63, w = tid >> 6;
  int lo = lane & 15, hi = lane >> 4;
  int bhc = (b * 16 + h) * 16 + c;
  int kv = h >> 2;
  f4 zero = {0.f, 0.f, 0.f, 0.f};
  f4 acc[2][8];
#pragma unroll
  for (int i = 0; i < 2; ++i)
#pragma unroll
    for (int j = 0; j < 8; ++j) acc[i][j] = zero;
#pragma unroll
  for (int kk = 0; kk < 8; ++kk){
    f4 d0 = *(const f4*)(dstv + (size_t)bhc * 256 + kk * 32 + hi * 8);
    f4 d1 = *(const f4*)(dstv + (size_t)bhc * 256 + kk * 32 + hi * 8 + 4);
    bf8 af[2];
#pragma unroll
    for (int pr = 0; pr < 2; ++pr){
      bf8 a = *(const bf8*)(xdtT + (size_t)bhc * 32768 + (w * 32 + pr * 16 + lo) * 256 + kk * 32 + hi * 8);
      bf8 ad;
#pragma unroll
      for (int j = 0; j < 4; ++j){
        ad[j]     = (short)f2b(b2f((u16t)a[j]) * d0[j]);
        ad[4 + j] = (short)f2b(b2f((u16t)a[4 + j]) * d1[j]);
      }
      af[pr] = ad;
    }
    bf8 bb[8];
#pragma unroll
    for (int nb = 0; nb < 8; ++nb)
      bb[nb] = *(const bf8*)(BgT + ((size_t)(b * 4 + kv) * 128 + nb * 16 + lo) * 4096 + c * 256 + kk * 32 + hi * 8);
#pragma unroll
    for (int pr = 0; pr < 2; ++pr)
#pragma unroll
      for (int nb = 0; nb < 8; ++nb)
        acc[pr][nb] = MFMA16(af[pr], bb[nb], acc[pr][nb]);
  }
#pragma unroll
  for (int pr = 0; pr < 2; ++pr)
#pragma unroll
    for (int nb = 0; nb < 8; ++nb)
#pragma unroll
      for (int i = 0; i < 4; ++i)
        states16[(size_t)bhc * 16384 + (w * 32 + pr * 16 + hi * 4 + i) * 128 + nb * 16 + lo]
          = f2b(acc[pr][nb][i]);
}

// ---------------------------------------------------------------- K7: inter-chunk scan
__global__ __launch_bounds__(256) void k_scan(const u16t* __restrict__ states16,
                                              const float* __restrict__ cdec,
                                              u16t* __restrict__ prevb){
  int h = blockIdx.x, b = blockIdx.y;
  int tid = threadIdx.x;
  int bh = b * 16 + h;
  float carry[64];
#pragma unroll
  for (int i = 0; i < 64; ++i) carry[i] = 0.f;
  for (int c = 0; c < 16; ++c){
    size_t base = ((size_t)bh * 16 + c) * 16384;
    float cd = cdec[bh * 16 + c];
#pragma unroll
    for (int i = 0; i < 64; ++i){
      size_t idx = base + i * 256 + tid;
      prevb[idx] = f2b(carry[i]);
      carry[i] = carry[i] * cd + b2f(states16[idx]);
    }
  }
}

// ---------------------------------------------------------------- K8: Y_off + Y_diag + gate + RMSNorm
__global__ __launch_bounds__(256) void k_fin(const u16t* __restrict__ Cg,
                                             const u16t* __restrict__ Bg,
                                             const u16t* __restrict__ xdtT,
                                             const u16t* __restrict__ prevb,
                                             const float* __restrict__ Acs,
                                             const u16t* __restrict__ z16,
                                             const u16t* __restrict__ xf16,
                                             const float* __restrict__ Dp,
                                             const float* __restrict__ nw,
                                             u16t* __restrict__ yn){
  int c = blockIdx.x, h = blockIdx.y, b = blockIdx.z;
  int tid = threadIdx.x, lane = tid & 63, w = tid >> 6;
  int lo = lane & 15, hi = lane >> 4;
  int bhc = (b * 16 + h) * 16 + c;
  int kv = h >> 2;
  int blbase = b * 4096 + c * 256;
  __shared__ float AcsS[256];
  __shared__ __align__(16) char Gb[4][8192];
  AcsS[tid] = Acs[(size_t)bhc * 256 + tid];
  __syncthreads();
  char* gw = Gb[w];
  f4 zero = {0.f, 0.f, 0.f, 0.f};
  f4 accY[4][8];
#pragma unroll
  for (int i = 0; i < 4; ++i)
#pragma unroll
    for (int j = 0; j < 8; ++j) accY[i][j] = zero;
  // ---- Y_off: (expA-scaled C) @ prev^T
#pragma unroll
  for (int kk = 0; kk < 4; ++kk){
    bf8 af[4], bb[8];
#pragma unroll
    for (int mb = 0; mb < 4; ++mb){
      int l = w * 64 + mb * 16 + lo;
      float ea = __expf(AcsS[l]);
      bf8 cr = *(const bf8*)(Cg + (size_t)(blbase + l) * 2048 + h * 128 + kk * 32 + hi * 8);
      bf8 cs;
#pragma unroll
      for (int j = 0; j < 8; ++j) cs[j] = (short)f2b(b2f((u16t)cr[j]) * ea);
      af[mb] = cs;
    }
#pragma unroll
    for (int pb = 0; pb < 8; ++pb)
      bb[pb] = *(const bf8*)(prevb + (size_t)bhc * 16384 + (pb * 16 + lo) * 128 + kk * 32 + hi * 8);
#pragma unroll
    for (int mb = 0; mb < 4; ++mb)
#pragma unroll
      for (int pb = 0; pb < 8; ++pb)
        accY[mb][pb] = MFMA16(af[mb], bb[pb], accY[mb][pb]);
  }
  // ---- Y_diag: per s-block G = C@B^T, mask+decay, then G @ xdt^T
  for (int sb = 0; sb <= w; ++sb){
    f4 g[4][4];
#pragma unroll
    for (int i = 0; i < 4; ++i)
#pragma unroll
      for (int j = 0; j < 4; ++j) g[i][j] = zero;
#pragma unroll
    for (int kk = 0; kk < 4; ++kk){
      bf8 af[4], bb[4];
#pragma unroll
      for (int mb = 0; mb < 4; ++mb)
        af[mb] = *(const bf8*)(Cg + (size_t)(blbase + w * 64 + mb * 16 + lo) * 2048 + h * 128 + kk * 32 + hi * 8);
#pragma unroll
      for (int nb = 0; nb < 4; ++nb)
        bb[nb] = *(const bf8*)(Bg + (size_t)(blbase + sb * 64 + nb * 16 + lo) * 512 + kv * 128 + kk * 32 + hi * 8);
#pragma unroll
      for (int mb = 0; mb < 4; ++mb)
#pragma unroll
        for (int nb = 0; nb < 4; ++nb)
          g[mb][nb] = MFMA16(af[mb], bb[nb], g[mb][nb]);
    }
#pragma unroll
    for (int mb = 0; mb < 4; ++mb)
#pragma unroll
      for (int nb = 0; nb < 4; ++nb)
#pragma unroll
        for (int i = 0; i < 4; ++i){
          int lrow = w * 64 + mb * 16 + hi * 4 + i;
          int scol = sb * 64 + nb * 16 + lo;
          float v = g[mb][nb][i];
          v = (scol <= lrow) ? v * __expf(AcsS[lrow] - AcsS[scol]) : 0.f;
          int rl = mb * 16 + hi * 4 + i;
          int off = ((rl << 7) + ((nb * 16 + lo) << 1)) ^ ((rl & 7) << 4);
          *(u16t*)(gw + off) = f2b(v);
        }
#pragma unroll
    for (int k2 = 0; k2 < 2; ++k2){
      bf8 a2[4], b2[8];
#pragma unroll
      for (int mb = 0; mb < 4; ++mb){
        int rl = mb * 16 + lo;
        int off = ((rl << 7) + (k2 << 6) + (hi << 4)) ^ ((rl & 7) << 4);
        a2[mb] = *(const bf8*)(gw + off);
      }
#pragma unroll
      for (int pb = 0; pb < 8; ++pb)
        b2[pb] = *(const bf8*)(xdtT + (size_t)bhc * 32768 + (pb * 16 + lo) * 256 + sb * 64 + k2 * 32 + hi * 8);
#pragma unroll
      for (int mb = 0; mb < 4; ++mb)
#pragma unroll
        for (int pb = 0; pb < 8; ++pb)
          accY[mb][pb] = MFMA16(a2[mb], b2[pb], accY[mb][pb]);
    }
  }
  // ---- epilogue: + D*x, gate by silu(z), per-head RMSNorm, bf16 out
  float Dh = Dp[h];
#pragma unroll
  for (int mb = 0; mb < 4; ++mb){
#pragma unroll
    for (int i = 0; i < 4; ++i){
      int lrow = w * 64 + mb * 16 + hi * 4 + i;
      size_t bl = (size_t)blbase + lrow;
      float gv[8];
      float ss = 0.f;
#pragma unroll
      for (int pb = 0; pb < 8; ++pb){
        int p = pb * 16 + lo;
        float y = accY[mb][pb][i] + Dh * b2f(xf16[bl * 512 + kv * 128 + p]);
        float z = b2f(z16[bl * 2048 + h * 128 + p]);
        float g = y * z * sigm(z);
        gv[pb] = g;
        ss += g * g;
      }
      ss += __shfl_xor(ss, 1);
      ss += __shfl_xor(ss, 2);
      ss += __shfl_xor(ss, 4);
      ss += __shfl_xor(ss, 8);
      float rstd = rsqrtf(ss * (1.f / 128.f) + 1e-5f);
#pragma unroll
      for (int pb = 0; pb < 8; ++pb){
        int p = pb * 16 + lo;
        yn[bl * 2048 + h * 128 + p] = f2b(gv[pb] * rstd * nw[h * 128 + p]);
      }
    }
  }
}

// ---------------------------------------------------------------- launch
extern "C" void kernel_launch(void* const* d_in, const int* in_sizes, int n_in,
                              void* d_out, int out_size, void* d_ws, size_t ws_size,
                              hipStream_t stream){
  const float* hs   = (const float*)d_in[0];
  const float* ipw  = (const float*)d_in[1];
  const float* cw   = (const float*)d_in[2];
  const float* cb   = (const float*)d_in[3];
  const float* dtb  = (const float*)d_in[4];
  const float* alog = (const float*)d_in[5];
  const float* Dp   = (const float*)d_in[6];
  const float* nw   = (const float*)d_in[7];
  const float* opw  = (const float*)d_in[8];
  float* out = (float*)d_out;

  char* base = (char*)d_ws;
  size_t o = 0;
  auto take = [&](size_t n) -> size_t { size_t r = o; o += (n + 255) & ~(size_t)255; return r; };

  // Region A: X16 (K0..K1) -> states16 + prevb (K6..K8)
  size_t offA = take(33554432);
  u16t* X16      = (u16t*)(base + offA);
  u16t* states16 = (u16t*)(base + offA);
  u16t* prevb    = (u16t*)(base + offA + 16777216);
  // Region B: Wp16 (K0..K1) -> BgT + dtv + Acs + dstv + cdec (K3..K8)
  size_t offB = take(21037056);
  u16t*  Wp16 = (u16t*)(base + offB);
  u16t*  BgT  = (u16t*)(base + offB);
  float* dtv  = (float*)(base + offB + 8388608);
  float* Acs  = (float*)(base + offB + 8912896);
  float* dstv = (float*)(base + offB + 9437184);
  float* cdec = (float*)(base + offB + 9961472);
  u16t*  Wo16 = (u16t*)(base + take(8388608));
  u16t*  z16  = (u16t*)(base + take(33554432));
  // Region C: xbc16 (K1..K2) -> yn16 (K8..K9)
  size_t offC = take(50331648);
  u16t* xbc16 = (u16t*)(base + offC);
  u16t* yn16  = (u16t*)(base + offC);
  float* dtraw = (float*)(base + take(524288));
  u16t*  xf16  = (u16t*)(base + take(8388608));
  u16t*  Bg    = (u16t*)(base + take(8388608));
  u16t*  Cgb   = (u16t*)(base + take(33554432));
  u16t*  xdtT  = (u16t*)(base + take(33554432));

  if (ws_size < o) return;  // budget guard: fail with clean absmax, not a fault

  k_cvt<<<16384, 256, 0, stream>>>(hs, X16, BLROWS * 2048 / 4);
  k_cvt<<<10272, 256, 0, stream>>>(ipw, Wp16, DPROJ * 2048 / 4);
  k_cvt<<<4096, 256, 0, stream>>>(opw, Wo16, 2048 * 2048 / 4);
  k_gemm_in<<<dim3(41, 64), 256, 0, stream>>>(X16, Wp16, z16, xbc16, dtraw);
  k_conv<<<dim3(12, BLROWS), 256, 0, stream>>>(xbc16, cw, cb, xf16, Bg, Cgb);
  k_dt<<<32, 256, 0, stream>>>(dtraw, dtb, dtv);
  k_prep<<<dim3(16, 16, 2), 256, 0, stream>>>(dtv, alog, Acs, dstv, cdec);
  k_repack<<<dim3(16, 16, 2), 256, 0, stream>>>(xf16, dtv, Bg, xdtT, BgT);
  k_states<<<dim3(16, 16, 2), 256, 0, stream>>>(xdtT, dstv, BgT, states16);
  k_scan<<<dim3(16, 2), 256, 0, stream>>>(states16, cdec, prevb);
  k_fin<<<dim3(16, 16, 2), 256, 0, stream>>>(Cgb, Bg, xdtT, prevb, Acs, z16, xf16, Dp, nw, yn16);
  k_gemm_out<<<dim3(16, 64), 256, 0, stream>>>(yn16, Wo16, out);
}

// Round 3
// 713.108 us; speedup vs baseline: 1.1319x; 1.1319x over previous
//
#include <hip/hip_runtime.h>

typedef unsigned short u16t;
typedef __attribute__((ext_vector_type(8))) short bf8;
typedef __attribute__((ext_vector_type(4))) float f4;

#define DEV __device__ __forceinline__

DEV u16t f2b(float f){
  unsigned u = __float_as_uint(f);
  u = (u + 0x7fffu + ((u >> 16) & 1u)) >> 16;
  return (u16t)u;
}
DEV float b2f(u16t u){ return __uint_as_float(((unsigned)u) << 16); }
DEV float sigm(float x){ return 1.f / (1.f + __expf(-x)); }

typedef __attribute__((address_space(1))) const void gas1;
typedef __attribute__((address_space(3))) void las3;
// async global->LDS, 16B/lane; LDS dest = wave-uniform base + lane*16
DEV void gl_lds16(const void* g, void* l){
  __builtin_amdgcn_global_load_lds((gas1*)g, (las3*)l, 16, 0, 0);
}

// B=2, SEQ=4096, D_MODEL=2048, D_INNER=2048, D_STATE=128, D_XB=512, D_CONV=4
// NHEADS=16, HEADDIM=128, NKV=4, N_REP=4, CHUNK=256, CONV_DIM=3072, D_IN_PROJ=5136
constexpr int KDIM   = 2048;
constexpr int DPROJ  = 5136;
constexpr int BLROWS = 8192;

#define MFMA16(a,b,c) __builtin_amdgcn_mfma_f32_16x16x32_bf16((a),(b),(c),0,0,0)

// ---------------------------------------------------------------- K0: f32->bf16
__global__ __launch_bounds__(256) void k_cvt(const float* __restrict__ src,
                                             u16t* __restrict__ dst, int n4){
  int i = blockIdx.x * 256 + threadIdx.x;
  if (i < n4){
    float4 v = ((const float4*)src)[i];
    ushort4 o;
    o.x = f2b(v.x); o.y = f2b(v.y); o.z = f2b(v.z); o.w = f2b(v.w);
    ((ushort4*)dst)[i] = o;
  }
}

// ---------------------------------------------------------------- K1: in_proj GEMM
// A[8192][2048] bf16, B[5136][2048] bf16 -> z16 / xbc16 / dtraw split outputs.
// global_load_lds staging, source pre-swizzled so swizzled ds_read is conflict-free.
__global__ __launch_bounds__(256) void k_gemm_in(const u16t* __restrict__ A,
                                                 const u16t* __restrict__ B,
                                                 u16t* __restrict__ z16,
                                                 u16t* __restrict__ xbc16,
                                                 float* __restrict__ dtraw){
  __shared__ __align__(16) char As[16384];
  __shared__ __align__(16) char Bs[16384];
  const int tid = threadIdx.x;
  const int lane = tid & 63, w = tid >> 6;
  const int lo = lane & 15, hi = lane >> 4;
  const int m0 = blockIdx.y << 7, n0 = blockIdx.x << 7;
  const int wr = (w >> 1) << 6, wc = (w & 1) << 6;
  const int srow = tid >> 3;                       // row within q-slab (0..31)
  const int kcol = ((tid & 7) ^ (srow & 7)) << 3;  // pre-swizzled k element offset
  f4 zero = {0.f, 0.f, 0.f, 0.f};
  f4 acc[4][4];
#pragma unroll
  for (int i = 0; i < 4; ++i)
#pragma unroll
    for (int j = 0; j < 4; ++j) acc[i][j] = zero;
  for (int kt = 0; kt < 32; ++kt){
#pragma unroll
    for (int q = 0; q < 4; ++q){
      int ra = m0 + q * 32 + srow;
      gl_lds16(A + (size_t)ra * KDIM + (kt << 6) + kcol, As + (q << 12) + (w << 10));
      int rb = n0 + q * 32 + srow;
      if (rb > DPROJ - 1) rb = DPROJ - 1;          // dup row; feeds only discarded cols
      gl_lds16(B + (size_t)rb * KDIM + (kt << 6) + kcol, Bs + (q << 12) + (w << 10));
    }
    __syncthreads();
#pragma unroll
    for (int kk = 0; kk < 2; ++kk){
      bf8 af[4], bb[4];
#pragma unroll
      for (int mb = 0; mb < 4; ++mb){
        int row = wr + mb * 16 + lo;
        int off = ((row << 7) + (kk << 6) + (hi << 4)) ^ ((row & 7) << 4);
        af[mb] = *(const bf8*)(As + off);
      }
#pragma unroll
      for (int nb = 0; nb < 4; ++nb){
        int row = wc + nb * 16 + lo;
        int off = ((row << 7) + (kk << 6) + (hi << 4)) ^ ((row & 7) << 4);
        bb[nb] = *(const bf8*)(Bs + off);
      }
#pragma unroll
      for (int mb = 0; mb < 4; ++mb)
#pragma unroll
        for (int nb = 0; nb < 4; ++nb)
          acc[mb][nb] = MFMA16(af[mb], bb[nb], acc[mb][nb]);
    }
    __syncthreads();
  }
  if (n0 < 2048){
#pragma unroll
    for (int mb = 0; mb < 4; ++mb)
#pragma unroll
      for (int nb = 0; nb < 4; ++nb)
#pragma unroll
        for (int i = 0; i < 4; ++i){
          int r = m0 + wr + mb * 16 + hi * 4 + i;
          int col = n0 + wc + nb * 16 + lo;
          z16[(size_t)r * 2048 + col] = f2b(acc[mb][nb][i]);
        }
  } else if (n0 < 5120){
#pragma unroll
    for (int mb = 0; mb < 4; ++mb)
#pragma unroll
      for (int nb = 0; nb < 4; ++nb)
#pragma unroll
        for (int i = 0; i < 4; ++i){
          int r = m0 + wr + mb * 16 + hi * 4 + i;
          int col = n0 + wc + nb * 16 + lo;
          xbc16[(size_t)r * 3072 + (col - 2048)] = f2b(acc[mb][nb][i]);
        }
  } else {
    if (wc == 0)
#pragma unroll
      for (int mb = 0; mb < 4; ++mb)
#pragma unroll
        for (int i = 0; i < 4; ++i){
          int r = m0 + wr + mb * 16 + hi * 4 + i;
          dtraw[(size_t)r * 16 + lo] = acc[mb][0][i];
        }
  }
}

// ---------------------------------------------------------------- K9: out_proj GEMM
__global__ __launch_bounds__(256) void k_gemm_out(const u16t* __restrict__ A,
                                                  const u16t* __restrict__ B,
                                                  float* __restrict__ C){
  __shared__ __align__(16) char As[16384];
  __shared__ __align__(16) char Bs[16384];
  const int tid = threadIdx.x;
  const int lane = tid & 63, w = tid >> 6;
  const int lo = lane & 15, hi = lane >> 4;
  const int m0 = blockIdx.y << 7, n0 = blockIdx.x << 7;
  const int wr = (w >> 1) << 6, wc = (w & 1) << 6;
  const int srow = tid >> 3;
  const int kcol = ((tid & 7) ^ (srow & 7)) << 3;
  f4 zero = {0.f, 0.f, 0.f, 0.f};
  f4 acc[4][4];
#pragma unroll
  for (int i = 0; i < 4; ++i)
#pragma unroll
    for (int j = 0; j < 4; ++j) acc[i][j] = zero;
  for (int kt = 0; kt < 32; ++kt){
#pragma unroll
    for (int q = 0; q < 4; ++q){
      gl_lds16(A + (size_t)(m0 + q * 32 + srow) * KDIM + (kt << 6) + kcol,
               As + (q << 12) + (w << 10));
      gl_lds16(B + (size_t)(n0 + q * 32 + srow) * KDIM + (kt << 6) + kcol,
               Bs + (q << 12) + (w << 10));
    }
    __syncthreads();
#pragma unroll
    for (int kk = 0; kk < 2; ++kk){
      bf8 af[4], bb[4];
#pragma unroll
      for (int mb = 0; mb < 4; ++mb){
        int row = wr + mb * 16 + lo;
        int off = ((row << 7) + (kk << 6) + (hi << 4)) ^ ((row & 7) << 4);
        af[mb] = *(const bf8*)(As + off);
      }
#pragma unroll
      for (int nb = 0; nb < 4; ++nb){
        int row = wc + nb * 16 + lo;
        int off = ((row << 7) + (kk << 6) + (hi << 4)) ^ ((row & 7) << 4);
        bb[nb] = *(const bf8*)(Bs + off);
      }
#pragma unroll
      for (int mb = 0; mb < 4; ++mb)
#pragma unroll
        for (int nb = 0; nb < 4; ++nb)
          acc[mb][nb] = MFMA16(af[mb], bb[nb], acc[mb][nb]);
    }
    __syncthreads();
  }
#pragma unroll
  for (int mb = 0; mb < 4; ++mb)
#pragma unroll
    for (int nb = 0; nb < 4; ++nb)
#pragma unroll
      for (int i = 0; i < 4; ++i){
        int r = m0 + wr + mb * 16 + hi * 4 + i;
        int col = n0 + wc + nb * 16 + lo;
        C[(size_t)r * 2048 + col] = acc[mb][nb][i];
      }
}

// ---------------------------------------------------------------- K2: conv + silu (x4 vectorized)
__global__ __launch_bounds__(256) void k_conv(const u16t* __restrict__ xbc,
                                              const float* __restrict__ cw,
                                              const float* __restrict__ cb,
                                              u16t* __restrict__ xf16,
                                              u16t* __restrict__ Bg,
                                              u16t* __restrict__ Cgb){
  int ch = (blockIdx.x * 256 + threadIdx.x) * 4;   // 0..3068 step 4
  int bl = blockIdx.y;
  int l = bl & 4095;
  const u16t* zc = xbc + (size_t)bl * 3072 + ch;
  float4 cbv = *(const float4*)(cb + ch);
  float4 w0 = *(const float4*)(cw + ch * 4);       // taps of channel ch
  float4 w1 = *(const float4*)(cw + ch * 4 + 4);   // ch+1
  float4 w2 = *(const float4*)(cw + ch * 4 + 8);   // ch+2
  float4 w3 = *(const float4*)(cw + ch * 4 + 12);  // ch+3
  float a0 = cbv.x, a1 = cbv.y, a2 = cbv.z, a3 = cbv.w;
  if (l >= 3){ ushort4 v = *(const ushort4*)(zc - 3 * 3072);
    a0 += b2f(v.x) * w0.x; a1 += b2f(v.y) * w1.x; a2 += b2f(v.z) * w2.x; a3 += b2f(v.w) * w3.x; }
  if (l >= 2){ ushort4 v = *(const ushort4*)(zc - 2 * 3072);
    a0 += b2f(v.x) * w0.y; a1 += b2f(v.y) * w1.y; a2 += b2f(v.z) * w2.y; a3 += b2f(v.w) * w3.y; }
  if (l >= 1){ ushort4 v = *(const ushort4*)(zc - 1 * 3072);
    a0 += b2f(v.x) * w0.z; a1 += b2f(v.y) * w1.z; a2 += b2f(v.z) * w2.z; a3 += b2f(v.w) * w3.z; }
  { ushort4 v = *(const ushort4*)(zc);
    a0 += b2f(v.x) * w0.w; a1 += b2f(v.y) * w1.w; a2 += b2f(v.z) * w2.w; a3 += b2f(v.w) * w3.w; }
  ushort4 o;
  o.x = f2b(a0 * sigm(a0)); o.y = f2b(a1 * sigm(a1));
  o.z = f2b(a2 * sigm(a2)); o.w = f2b(a3 * sigm(a3));
  if (ch < 512)       *(ushort4*)(xf16 + (size_t)bl * 512 + ch) = o;
  else if (ch < 1024) *(ushort4*)(Bg + (size_t)bl * 512 + (ch - 512)) = o;
  else                *(ushort4*)(Cgb + (size_t)bl * 2048 + (ch - 1024)) = o;
}

// ---------------------------------------------------------------- K3: dt softplus
__global__ __launch_bounds__(256) void k_dt(const float* __restrict__ dtraw,
                                            const float* __restrict__ dtb,
                                            float* __restrict__ dtv){
  int bl = blockIdx.x * 256 + threadIdx.x;
  int b = bl >> 12, l = bl & 4095;
#pragma unroll
  for (int h = 0; h < 16; ++h){
    float x = dtraw[(size_t)bl * 16 + h] + dtb[h];
    float sp = (x > 15.f) ? x : log1pf(__expf(x));
    dtv[((size_t)(b * 16 + h)) * 4096 + l] = sp;
  }
}

// ---------------------------------------------------------------- K4: chunk cumsum
__global__ __launch_bounds__(256) void k_prep(const float* __restrict__ dtv,
                                              const float* __restrict__ alog,
                                              float* __restrict__ Acs,
                                              float* __restrict__ dstv,
                                              float* __restrict__ cdec){
  int c = blockIdx.x, h = blockIdx.y, b = blockIdx.z;
  int tid = threadIdx.x;
  int bhc = (b * 16 + h) * 16 + c;
  __shared__ float sb_[2][256];
  float An = -__expf(alog[h]);
  float dA = dtv[((size_t)(b * 16 + h)) * 4096 + c * 256 + tid] * An;
  sb_[0][tid] = dA;
  __syncthreads();
  int src = 0;
  for (int off = 1; off < 256; off <<= 1){
    float v = sb_[src][tid];
    if (tid >= off) v += sb_[src][tid - off];
    sb_[src ^ 1][tid] = v;
    __syncthreads();
    src ^= 1;
  }
  float a = sb_[src][tid];
  float ae = sb_[src][255];
  Acs[(size_t)bhc * 256 + tid]  = a;
  dstv[(size_t)bhc * 256 + tid] = __expf(ae - a);
  if (tid == 0) cdec[bhc] = __expf(ae);
}

// ---------------------------------------------------------------- K5: repack transposes
__global__ __launch_bounds__(256) void k_repack(const u16t* __restrict__ xf16,
                                                const float* __restrict__ dtv,
                                                const u16t* __restrict__ Bg,
                                                u16t* __restrict__ xdtT,
                                                u16t* __restrict__ BgT){
  int c = blockIdx.x, h = blockIdx.y, b = blockIdx.z;
  int tid = threadIdx.x;
  int bhc = (b * 16 + h) * 16 + c;
  int kv = h >> 2;
  __shared__ float tile[128][65];
  for (int st = 0; st < 4; ++st){
#pragma unroll
    for (int i = 0; i < 32; ++i){
      int idx = i * 256 + tid;
      int sl = idx >> 7, p = idx & 127;
      int l = c * 256 + st * 64 + sl;
      size_t bl = (size_t)b * 4096 + l;
      tile[p][sl] = b2f(xf16[bl * 512 + kv * 128 + p]) * dtv[((size_t)(b * 16 + h)) * 4096 + l];
    }
    __syncthreads();
#pragma unroll
    for (int i = 0; i < 32; ++i){
      int idx = i * 256 + tid;
      int p = idx >> 6, sl = idx & 63;
      xdtT[(size_t)bhc * 32768 + p * 256 + st * 64 + sl] = f2b(tile[p][sl]);
    }
    __syncthreads();
  }
  if (h < 4){
    for (int st = 0; st < 4; ++st){
#pragma unroll
      for (int i = 0; i < 32; ++i){
        int idx = i * 256 + tid;
        int sl = idx >> 7, n = idx & 127;
        size_t bl = (size_t)b * 4096 + c * 256 + st * 64 + sl;
        tile[n][sl] = (float)Bg[bl * 512 + h * 128 + n];
      }
      __syncthreads();
#pragma unroll
      for (int i = 0; i < 32; ++i){
        int idx = i * 256 + tid;
        int n = idx >> 6, sl = idx & 63;
        BgT[((size_t)(b * 4 + h) * 128 + n) * 4096 + c * 256 + st * 64 + sl] = (u16t)tile[n][sl];
      }
      __syncthreads();
    }
  }
}

// ---------------------------------------------------------------- K6: chunk states
__global__ __launch_bounds__(256) void k_states(const u16t* __restrict__ xdtT,
                                                const float* __restrict__ dstv,
                                                const u16t* __restrict__ BgT,
                                                u16t* __restrict__ states16){
  int c = blockIdx.x, h = blockIdx.y, b = blockIdx.z;
  int tid = threadIdx.x, lane = tid & 63, w = tid >> 6;
  int lo = lane & 15, hi = lane >> 4;
  int bhc = (b * 16 + h) * 16 + c;
  int kv = h >> 2;
  f4 zero = {0.f, 0.f, 0.f, 0.f};
  f4 acc[2][8];
#pragma unroll
  for (int i = 0; i < 2; ++i)
#pragma unroll
    for (int j = 0; j < 8; ++j) acc[i][j] = zero;
#pragma unroll
  for (int kk = 0; kk < 8; ++kk){
    f4 d0 = *(const f4*)(dstv + (size_t)bhc * 256 + kk * 32 + hi * 8);
    f4 d1 = *(const f4*)(dstv + (size_t)bhc * 256 + kk * 32 + hi * 8 + 4);
    bf8 af[2];
#pragma unroll
    for (int pr = 0; pr < 2; ++pr){
      bf8 a = *(const bf8*)(xdtT + (size_t)bhc * 32768 + (w * 32 + pr * 16 + lo) * 256 + kk * 32 + hi * 8);
      bf8 ad;
#pragma unroll
      for (int j = 0; j < 4; ++j){
        ad[j]     = (short)f2b(b2f((u16t)a[j]) * d0[j]);
        ad[4 + j] = (short)f2b(b2f((u16t)a[4 + j]) * d1[j]);
      }
      af[pr] = ad;
    }
    bf8 bb[8];
#pragma unroll
    for (int nb = 0; nb < 8; ++nb)
      bb[nb] = *(const bf8*)(BgT + ((size_t)(b * 4 + kv) * 128 + nb * 16 + lo) * 4096 + c * 256 + kk * 32 + hi * 8);
#pragma unroll
    for (int pr = 0; pr < 2; ++pr)
#pragma unroll
      for (int nb = 0; nb < 8; ++nb)
        acc[pr][nb] = MFMA16(af[pr], bb[nb], acc[pr][nb]);
  }
#pragma unroll
  for (int pr = 0; pr < 2; ++pr)
#pragma unroll
    for (int nb = 0; nb < 8; ++nb)
#pragma unroll
      for (int i = 0; i < 4; ++i)
        states16[(size_t)bhc * 16384 + (w * 32 + pr * 16 + hi * 4 + i) * 128 + nb * 16 + lo]
          = f2b(acc[pr][nb][i]);
}

// ---------------------------------------------------------------- K7: inter-chunk scan (8x parallel)
__global__ __launch_bounds__(256) void k_scan(const u16t* __restrict__ states16,
                                              const float* __restrict__ cdec,
                                              u16t* __restrict__ prevb){
  int h = blockIdx.x, b = blockIdx.y, sl = blockIdx.z;
  int tid = threadIdx.x;
  int bh = b * 16 + h;
  float carry[8];
#pragma unroll
  for (int i = 0; i < 8; ++i) carry[i] = 0.f;
  for (int c = 0; c < 16; ++c){
    size_t base = ((size_t)bh * 16 + c) * 16384 + sl * 2048;
    float cd = cdec[bh * 16 + c];
#pragma unroll
    for (int i = 0; i < 8; ++i){
      size_t idx = base + i * 256 + tid;
      prevb[idx] = f2b(carry[i]);
      carry[i] = carry[i] * cd + b2f(states16[idx]);
    }
  }
}

// ---------------------------------------------------------------- K8: Y_off + Y_diag + gate + RMSNorm
__global__ __launch_bounds__(256) void k_fin(const u16t* __restrict__ Cg,
                                             const u16t* __restrict__ Bg,
                                             const u16t* __restrict__ xdtT,
                                             const u16t* __restrict__ prevb,
                                             const float* __restrict__ Acs,
                                             const u16t* __restrict__ z16,
                                             const u16t* __restrict__ xf16,
                                             const float* __restrict__ Dp,
                                             const float* __restrict__ nw,
                                             u16t* __restrict__ yn){
  int c = blockIdx.x, h = blockIdx.y, b = blockIdx.z;
  int tid = threadIdx.x, lane = tid & 63, w = tid >> 6;
  int lo = lane & 15, hi = lane >> 4;
  int bhc = (b * 16 + h) * 16 + c;
  int kv = h >> 2;
  int blbase = b * 4096 + c * 256;
  __shared__ float AcsS[256];
  __shared__ __align__(16) char Gb[4][8192];
  AcsS[tid] = Acs[(size_t)bhc * 256 + tid];
  __syncthreads();
  char* gw = Gb[w];
  f4 zero = {0.f, 0.f, 0.f, 0.f};
  f4 accY[4][8];
#pragma unroll
  for (int i = 0; i < 4; ++i)
#pragma unroll
    for (int j = 0; j < 8; ++j) accY[i][j] = zero;
  // ---- Y_off: (expA-scaled C) @ prev^T
#pragma unroll
  for (int kk = 0; kk < 4; ++kk){
    bf8 af[4], bb[8];
#pragma unroll
    for (int mb = 0; mb < 4; ++mb){
      int l = w * 64 + mb * 16 + lo;
      float ea = __expf(AcsS[l]);
      bf8 cr = *(const bf8*)(Cg + (size_t)(blbase + l) * 2048 + h * 128 + kk * 32 + hi * 8);
      bf8 cs;
#pragma unroll
      for (int j = 0; j < 8; ++j) cs[j] = (short)f2b(b2f((u16t)cr[j]) * ea);
      af[mb] = cs;
    }
#pragma unroll
    for (int pb = 0; pb < 8; ++pb)
      bb[pb] = *(const bf8*)(prevb + (size_t)bhc * 16384 + (pb * 16 + lo) * 128 + kk * 32 + hi * 8);
#pragma unroll
    for (int mb = 0; mb < 4; ++mb)
#pragma unroll
      for (int pb = 0; pb < 8; ++pb)
        accY[mb][pb] = MFMA16(af[mb], bb[pb], accY[mb][pb]);
  }
  // ---- Y_diag: per s-block G = C@B^T, mask+decay, then G @ xdt^T
  for (int sb = 0; sb <= w; ++sb){
    f4 g[4][4];
#pragma unroll
    for (int i = 0; i < 4; ++i)
#pragma unroll
      for (int j = 0; j < 4; ++j) g[i][j] = zero;
#pragma unroll
    for (int kk = 0; kk < 4; ++kk){
      bf8 af[4], bb[4];
#pragma unroll
      for (int mb = 0; mb < 4; ++mb)
        af[mb] = *(const bf8*)(Cg + (size_t)(blbase + w * 64 + mb * 16 + lo) * 2048 + h * 128 + kk * 32 + hi * 8);
#pragma unroll
      for (int nb = 0; nb < 4; ++nb)
        bb[nb] = *(const bf8*)(Bg + (size_t)(blbase + sb * 64 + nb * 16 + lo) * 512 + kv * 128 + kk * 32 + hi * 8);
#pragma unroll
      for (int mb = 0; mb < 4; ++mb)
#pragma unroll
        for (int nb = 0; nb < 4; ++nb)
          g[mb][nb] = MFMA16(af[mb], bb[nb], g[mb][nb]);
    }
#pragma unroll
    for (int mb = 0; mb < 4; ++mb)
#pragma unroll
      for (int nb = 0; nb < 4; ++nb)
#pragma unroll
        for (int i = 0; i < 4; ++i){
          int lrow = w * 64 + mb * 16 + hi * 4 + i;
          int scol = sb * 64 + nb * 16 + lo;
          float v = g[mb][nb][i];
          v = (scol <= lrow) ? v * __expf(AcsS[lrow] - AcsS[scol]) : 0.f;
          int rl = mb * 16 + hi * 4 + i;
          int off = ((rl << 7) + ((nb * 16 + lo) << 1)) ^ ((rl & 7) << 4);
          *(u16t*)(gw + off) = f2b(v);
        }
#pragma unroll
    for (int k2 = 0; k2 < 2; ++k2){
      bf8 a2[4], b2[8];
#pragma unroll
      for (int mb = 0; mb < 4; ++mb){
        int rl = mb * 16 + lo;
        int off = ((rl << 7) + (k2 << 6) + (hi << 4)) ^ ((rl & 7) << 4);
        a2[mb] = *(const bf8*)(gw + off);
      }
#pragma unroll
      for (int pb = 0; pb < 8; ++pb)
        b2[pb] = *(const bf8*)(xdtT + (size_t)bhc * 32768 + (pb * 16 + lo) * 256 + sb * 64 + k2 * 32 + hi * 8);
#pragma unroll
      for (int mb = 0; mb < 4; ++mb)
#pragma unroll
        for (int pb = 0; pb < 8; ++pb)
          accY[mb][pb] = MFMA16(a2[mb], b2[pb], accY[mb][pb]);
    }
  }
  // ---- epilogue: + D*x, gate by silu(z), per-head RMSNorm, bf16 out
  float Dh = Dp[h];
#pragma unroll
  for (int mb = 0; mb < 4; ++mb){
#pragma unroll
    for (int i = 0; i < 4; ++i){
      int lrow = w * 64 + mb * 16 + hi * 4 + i;
      size_t bl = (size_t)blbase + lrow;
      float gv[8];
      float ss = 0.f;
#pragma unroll
      for (int pb = 0; pb < 8; ++pb){
        int p = pb * 16 + lo;
        float y = accY[mb][pb][i] + Dh * b2f(xf16[bl * 512 + kv * 128 + p]);
        float z = b2f(z16[bl * 2048 + h * 128 + p]);
        float g = y * z * sigm(z);
        gv[pb] = g;
        ss += g * g;
      }
      ss += __shfl_xor(ss, 1);
      ss += __shfl_xor(ss, 2);
      ss += __shfl_xor(ss, 4);
      ss += __shfl_xor(ss, 8);
      float rstd = rsqrtf(ss * (1.f / 128.f) + 1e-5f);
#pragma unroll
      for (int pb = 0; pb < 8; ++pb){
        int p = pb * 16 + lo;
        yn[bl * 2048 + h * 128 + p] = f2b(gv[pb] * rstd * nw[h * 128 + p]);
      }
    }
  }
}

// ---------------------------------------------------------------- launch
extern "C" void kernel_launch(void* const* d_in, const int* in_sizes, int n_in,
                              void* d_out, int out_size, void* d_ws, size_t ws_size,
                              hipStream_t stream){
  const float* hs   = (const float*)d_in[0];
  const float* ipw  = (const float*)d_in[1];
  const float* cw   = (const float*)d_in[2];
  const float* cb   = (const float*)d_in[3];
  const float* dtb  = (const float*)d_in[4];
  const float* alog = (const float*)d_in[5];
  const float* Dp   = (const float*)d_in[6];
  const float* nw   = (const float*)d_in[7];
  const float* opw  = (const float*)d_in[8];
  float* out = (float*)d_out;

  char* base = (char*)d_ws;
  size_t o = 0;
  auto take = [&](size_t n) -> size_t { size_t r = o; o += (n + 255) & ~(size_t)255; return r; };

  // Region A: X16 (K0..K1) -> states16 + prevb (K6..K8)
  size_t offA = take(33554432);
  u16t* X16      = (u16t*)(base + offA);
  u16t* states16 = (u16t*)(base + offA);
  u16t* prevb    = (u16t*)(base + offA + 16777216);
  // Region B: Wp16 (K0..K1) -> BgT + dtv + Acs + dstv + cdec (K3..K8)
  size_t offB = take(21037056);
  u16t*  Wp16 = (u16t*)(base + offB);
  u16t*  BgT  = (u16t*)(base + offB);
  float* dtv  = (float*)(base + offB + 8388608);
  float* Acs  = (float*)(base + offB + 8912896);
  float* dstv = (float*)(base + offB + 9437184);
  float* cdec = (float*)(base + offB + 9961472);
  u16t*  Wo16 = (u16t*)(base + take(8388608));
  u16t*  z16  = (u16t*)(base + take(33554432));
  // Region C: xbc16 (K1..K2) -> yn16 (K8..K9)
  size_t offC = take(50331648);
  u16t* xbc16 = (u16t*)(base + offC);
  u16t* yn16  = (u16t*)(base + offC);
  float* dtraw = (float*)(base + take(524288));
  u16t*  xf16  = (u16t*)(base + take(8388608));
  u16t*  Bg    = (u16t*)(base + take(8388608));
  u16t*  Cgb   = (u16t*)(base + take(33554432));
  u16t*  xdtT  = (u16t*)(base + take(33554432));

  if (ws_size < o) return;  // budget guard

  k_cvt<<<16384, 256, 0, stream>>>(hs, X16, BLROWS * 2048 / 4);
  k_cvt<<<10272, 256, 0, stream>>>(ipw, Wp16, DPROJ * 2048 / 4);
  k_cvt<<<4096, 256, 0, stream>>>(opw, Wo16, 2048 * 2048 / 4);
  k_gemm_in<<<dim3(41, 64), 256, 0, stream>>>(X16, Wp16, z16, xbc16, dtraw);
  k_conv<<<dim3(3, BLROWS), 256, 0, stream>>>(xbc16, cw, cb, xf16, Bg, Cgb);
  k_dt<<<32, 256, 0, stream>>>(dtraw, dtb, dtv);
  k_prep<<<dim3(16, 16, 2), 256, 0, stream>>>(dtv, alog, Acs, dstv, cdec);
  k_repack<<<dim3(16, 16, 2), 256, 0, stream>>>(xf16, dtv, Bg, xdtT, BgT);
  k_states<<<dim3(16, 16, 2), 256, 0, stream>>>(xdtT, dstv, BgT, states16);
  k_scan<<<dim3(16, 2, 8), 256, 0, stream>>>(states16, cdec, prevb);
  k_fin<<<dim3(16, 16, 2), 256, 0, stream>>>(Cgb, Bg, xdtT, prevb, Acs, z16, xf16, Dp, nw, yn16);
  k_gemm_out<<<dim3(16, 64), 256, 0, stream>>>(yn16, Wo16, out);
}